// Round 5
// baseline (315.971 us; speedup 1.0000x reference)
//
#include <hip/hip_runtime.h>
#include <stdint.h>

// Problem constants
#define B_SZ   8192
#define IN_DIM 320      // S + A
#define H_DIM  1024
#define E_NUM  8
#define OUT_DIM 257     // S + 1
#define TM     64
#define MAXT   (B_SZ / TM + E_NUM)   // 136 — worst-case M-tile count
#define W3ROWS 320                   // layer-3 N padded to 5 x 64
#define NG12   (MAXT * 16)           // 2176 gemm blocks, layers 1/2
#define NG3    (MAXT * 5)            // 680 gemm blocks, layer 3
#define NAUX   2568                  // 2048 W2T + 512 W3T + 8 rcol

typedef __bf16 bf16x8 __attribute__((ext_vector_type(8)));
typedef float  f32x4  __attribute__((ext_vector_type(4)));

__device__ __forceinline__ unsigned short f2bf(float f) {
    unsigned int u = __float_as_uint(f);
    return (unsigned short)((u + 0x7fffu + ((u >> 16) & 1u)) >> 16);  // RNE
}

// ---------------------------------------------------------------------------
// 64x64 transpose-convert: src (e,Ks,Ns) f32 tile (kt,nt) -> dst (e,dR,Ks)
// bf16. VEC: float4 phase-1 loads (requires Ns%4==0). sh: 64*66 ushorts.
template <int NT, bool VEC>
__device__ __forceinline__ void trans64(const float* __restrict__ src,
                                        unsigned short* __restrict__ dst,
                                        int Ks, int Ns, int dR, int e, int kt,
                                        int nt, unsigned short* sh, int tid) {
    int k0 = kt * 64, n0 = nt * 64;
    const float* s = src + (size_t)e * Ks * Ns + (size_t)k0 * Ns + n0;
    unsigned short* d = dst + ((size_t)e * dR + n0) * Ks + k0;
    if (VEC) {
        int c4 = tid & 15, r0 = tid >> 4;            // NT/16 rows per step
        for (int r = r0; r < 64; r += NT / 16) {
            float4 v = *(const float4*)&s[(size_t)r * Ns + c4 * 4];
            ushort4 o;
            o.x = f2bf(v.x); o.y = f2bf(v.y); o.z = f2bf(v.z); o.w = f2bf(v.w);
            *(ushort4*)&sh[r * 66 + c4 * 4] = o;
        }
    } else {
        int tx = tid & 63;
        for (int r = tid >> 6; r < 64; r += NT / 64)
            sh[r * 66 + tx] = f2bf(s[(size_t)r * Ns + tx]);
    }
    __syncthreads();
    int kq = tid & 15;
    for (int n = tid >> 4; n < 64; n += NT / 16) {
        ushort4 o;
        o.x = sh[(kq * 4 + 0) * 66 + n];
        o.y = sh[(kq * 4 + 1) * 66 + n];
        o.z = sh[(kq * 4 + 2) * 66 + n];
        o.w = sh[(kq * 4 + 3) * 66 + n];
        *(ushort4*)&d[(size_t)n * Ks + kq * 4] = o;
    }
}

// ---------------------------------------------------------------------------
// prep0: bucket + x-convert + W1 transpose.  256 threads.
// grid: 1 (bucket) + 320 (xconv) + 640 (W1T) = 961
__global__ __launch_bounds__(256)
void k_prep0(const float* __restrict__ state, const float* __restrict__ action,
             const int* __restrict__ idx, const float* __restrict__ W1,
             unsigned short* __restrict__ xb, unsigned short* __restrict__ w1t,
             int* __restrict__ order, int* __restrict__ te,
             int* __restrict__ tp0, int* __restrict__ tcnt) {
    __shared__ unsigned short sh[64 * 66];
    __shared__ int scnt[16][E_NUM];
    int bid = blockIdx.x, tid = threadIdx.x;

    if (bid == 0) {
        int shard = tid & 15;
        if (tid < 128) ((int*)scnt)[tid] = 0;
        __syncthreads();
        for (int b = tid; b < B_SZ; b += 256) atomicAdd(&scnt[shard][idx[b]], 1);
        __syncthreads();
        if (tid == 0) {
            int pos = 0, tt = 0;
            for (int e = 0; e < E_NUM; e++) {
                int start = pos;
                for (int s = 0; s < 16; s++) { int c = scnt[s][e]; scnt[s][e] = pos; pos += c; }
                int tot = pos - start;
                for (int st = 0; st < tot; st += TM) {
                    te[tt] = e; tp0[tt] = start + st; tcnt[tt] = min(TM, tot - st); tt++;
                }
            }
            for (; tt < MAXT; tt++) { te[tt] = 0; tp0[tt] = 0; tcnt[tt] = 0; }
        }
        __syncthreads();
        for (int b = tid; b < B_SZ; b += 256) {
            int e = idx[b];
            int p = atomicAdd(&scnt[shard][e], 1);
            order[p] = b;
        }
        return;
    }

    if (bid <= 320) {
        // x = concat(state, action) -> bf16; 2048 quads/block (exact: 320*2048)
        int a = bid - 1;
        const float4* sf = (const float4*)state;
        const float4* af = (const float4*)action;
#pragma unroll
        for (int p = 0; p < 8; p++) {
            int q = a * 2048 + p * 256 + tid;     // quad id: b*80 + j
            int b = q / 80, j = q % 80;
            float4 v = (j < 64) ? sf[b * 64 + j] : af[b * 16 + (j - 64)];
            ushort4 o;
            o.x = f2bf(v.x); o.y = f2bf(v.y); o.z = f2bf(v.z); o.w = f2bf(v.w);
            ((ushort4*)xb)[q] = o;
        }
        return;
    }

    // W1 transpose: (8,320,1024) -> (8,1024,320); 80 tiles/e
    int c = bid - 321;
    int e = c / 80, m = c % 80;
    trans64<256, true>(W1, w1t, IN_DIM, H_DIM, H_DIM, e, m / 16, m % 16, sh, tid);
}

// ---------------------------------------------------------------------------
// Grouped GEMM, barrier-free: single-wave (64 thr) blocks, 64x64 tile,
// direct global->VGPR fragment loads (no LDS staging). A (rows,K) bf16,
// Wt (E,wtRows,K) bf16 N-major: one global_load_dwordx4 per fragment.
// Fully unrolled K-loop -> compiler interleaves MFMA with loads under
// fine-grained s_waitcnt vmcnt(N) (AITER-style pipeline, no barrier drain).
// MODE 0: Hout[(p0+m)*1024 + n] = bf16(relu(acc + bias))
// MODE 1: n<256 -> Out[row*256+n] = state+acc+b; n==256 -> reward; else drop.
// AUX: blocks [ng, ng+2568) do W2/W3 transpose + W3 reward column instead.
template <int K, bool GATHER, int MODE, bool AUX>
__global__ __launch_bounds__(64, 2)
void k_gemm(const unsigned short* __restrict__ Abase,
            const unsigned short* __restrict__ Wt, int wtRows,
            const float* __restrict__ bias, int bstride,
            unsigned short* __restrict__ Hout,
            float* __restrict__ Out, const float* __restrict__ state,
            const int* __restrict__ order,
            const int* __restrict__ te, const int* __restrict__ tp0,
            const int* __restrict__ tcnt, int ng,
            const float* __restrict__ W2, unsigned short* __restrict__ w2t,
            const float* __restrict__ W3, unsigned short* __restrict__ w3t) {
    int bid = blockIdx.x, lane = threadIdx.x;

    if (AUX && bid >= ng) {
        __shared__ unsigned short sh[64 * 66];
        int a = bid - ng;
        if (a < 2048) {          // W2: (8,1024,1024) -> (8,1024,1024)
            trans64<64, true>(W2, w2t, H_DIM, H_DIM, H_DIM, a >> 8,
                              (a & 255) >> 4, a & 15, sh, lane);
        } else if (a < 2560) {   // W3 cols 0..255: (8,1024,257) -> (8,320,1024)
            int b = a - 2048;
            trans64<64, false>(W3, w3t, H_DIM, OUT_DIM, W3ROWS, b >> 6,
                               (b & 63) >> 2, b & 3, sh, lane);
        } else {                 // W3 reward column -> w3t row 256 (8 blocks)
            int e = a - 2560;
#pragma unroll
            for (int p = 0; p < 16; p++) {
                int k = p * 64 + lane;
                w3t[((size_t)e * W3ROWS + 256) * H_DIM + k] =
                    f2bf(W3[((size_t)e * H_DIM + k) * OUT_DIM + 256]);
            }
        }
        return;
    }

    int t = bid % MAXT, ny = bid / MAXT;
    int cnt = tcnt[t];
    if (cnt == 0) return;
    int e = te[t], p0 = tp0[t];
    int n0 = ny * 64;

    const int fm = lane & 15;          // fragment row (m or n)
    const int kc = lane >> 4;          // k-chunk (x8 bf16)

    // A-row addresses per fragment (gather resolved once)
    size_t arow[4];
#pragma unroll
    for (int i = 0; i < 4; i++) {
        int m = i * 16 + fm;
        int rc = m < cnt ? m : cnt - 1;              // clamp; masked in epilogue
        arow[i] = GATHER ? (size_t)order[p0 + rc] : (size_t)(p0 + rc);
    }
    const unsigned short* aB = Abase + kc * 8;
    const unsigned short* bB = Wt + ((size_t)e * wtRows + n0 + fm) * K + kc * 8;

    f32x4 acc[4][4];
#pragma unroll
    for (int i = 0; i < 4; i++)
#pragma unroll
        for (int j = 0; j < 4; j++) acc[i][j] = (f32x4)0.f;

#pragma unroll
    for (int k0 = 0; k0 < K; k0 += 32) {
        bf16x8 af[4], bf[4];
#pragma unroll
        for (int i = 0; i < 4; i++)
            af[i] = *(const bf16x8*)(aB + arow[i] * K + k0);
#pragma unroll
        for (int j = 0; j < 4; j++)
            bf[j] = *(const bf16x8*)(bB + (size_t)j * 16 * K + k0);
#pragma unroll
        for (int i = 0; i < 4; i++)
#pragma unroll
            for (int j = 0; j < 4; j++)
                acc[i][j] = __builtin_amdgcn_mfma_f32_16x16x32_bf16(
                    af[i], bf[j], acc[i][j], 0, 0, 0);
    }

    // epilogue: C/D mapping col = lane&15, row = (lane>>4)*4 + reg
    int col = lane & 15, rq = lane >> 4;
#pragma unroll
    for (int j = 0; j < 4; j++) {
        int n = n0 + j * 16 + col;
        float bv = (MODE == 0) ? bias[e * bstride + n]
                               : ((n <= 256) ? bias[e * bstride + n] : 0.f);
#pragma unroll
        for (int i = 0; i < 4; i++) {
#pragma unroll
            for (int rr = 0; rr < 4; rr++) {
                int m = i * 16 + rq * 4 + rr;
                if (m < cnt) {
                    float v = acc[i][j][rr] + bv;
                    if (MODE == 0) {
                        Hout[(size_t)(p0 + m) * H_DIM + n] = f2bf(fmaxf(v, 0.f));
                    } else {
                        int row = order[p0 + m];
                        if (n < 256) {
                            size_t o = (size_t)row * 256 + n;
                            Out[o] = state[o] + v;
                        } else if (n == 256) {
                            Out[(size_t)B_SZ * 256 + row] = v;   // reward
                        }
                    }
                }
            }
        }
    }
}

// ---------------------------------------------------------------------------
extern "C" void kernel_launch(void* const* d_in, const int* in_sizes, int n_in,
                              void* d_out, int out_size, void* d_ws, size_t ws_size,
                              hipStream_t stream) {
    const float* state  = (const float*)d_in[0];
    const float* action = (const float*)d_in[1];
    const int*   idx    = (const int*)d_in[2];
    const float* W1     = (const float*)d_in[3];
    const float* b1     = (const float*)d_in[4];
    const float* W2     = (const float*)d_in[5];
    const float* b2     = (const float*)d_in[6];
    const float* W3     = (const float*)d_in[7];
    const float* b3     = (const float*)d_in[8];
    float* out = (float*)d_out;

    char* ws = (char*)d_ws;
    size_t off = 0;
    auto alloc = [&](size_t bytes) -> void* {
        void* p = ws + off;
        off = (off + bytes + 255) & ~(size_t)255;
        return p;
    };
    unsigned short* xb  = (unsigned short*)alloc((size_t)B_SZ * IN_DIM * 2);
    unsigned short* w1t = (unsigned short*)alloc((size_t)E_NUM * H_DIM * IN_DIM * 2);
    unsigned short* w2t = (unsigned short*)alloc((size_t)E_NUM * H_DIM * H_DIM * 2);
    unsigned short* w3t = (unsigned short*)alloc((size_t)E_NUM * W3ROWS * H_DIM * 2);
    unsigned short* h1  = (unsigned short*)alloc((size_t)B_SZ * H_DIM * 2);
    unsigned short* h2  = (unsigned short*)alloc((size_t)B_SZ * H_DIM * 2);
    int* order = (int*)alloc(B_SZ * 4);
    int* te    = (int*)alloc(MAXT * 4);
    int* tp0   = (int*)alloc(MAXT * 4);
    int* tcnt  = (int*)alloc(MAXT * 4);

    // prep0: bucket + x-convert + W1 transpose
    k_prep0<<<961, 256, 0, stream>>>(state, action, idx, W1, xb, w1t,
                                     order, te, tp0, tcnt);

    // layer 1 gemm (2176 blocks) + overlapped W2/W3 transposes (2568 blocks)
    k_gemm<IN_DIM, true, 0, true><<<NG12 + NAUX, 64, 0, stream>>>(
        xb, w1t, H_DIM, b1, H_DIM, h1, nullptr, nullptr, order, te, tp0, tcnt,
        NG12, W2, w2t, W3, w3t);
    // layer 2
    k_gemm<H_DIM, false, 0, false><<<NG12, 64, 0, stream>>>(
        h1, w2t, H_DIM, b2, H_DIM, h2, nullptr, nullptr, order, te, tp0, tcnt,
        NG12, nullptr, nullptr, nullptr, nullptr);
    // layer 3 + fused reward: (B,1024) x (1024, 320-padded)
    k_gemm<H_DIM, false, 1, false><<<NG3, 64, 0, stream>>>(
        h2, w3t, W3ROWS, b3, OUT_DIM, nullptr, out, state, order, te, tp0, tcnt,
        NG3, nullptr, nullptr, nullptr, nullptr);
}

// Round 6
// 239.344 us; speedup vs baseline: 1.3202x; 1.3202x over previous
//
#include <hip/hip_runtime.h>
#include <stdint.h>

// Problem constants
#define B_SZ   8192
#define IN_DIM 320      // S + A
#define H_DIM  1024
#define E_NUM  8
#define OUT_DIM 257     // S + 1
#define TM     128
#define MT_MAX 64       // worst-case M-tiles per expert (all rows one expert)
#define W3ROWS 384      // layer-3 N padded to 3 x 128

typedef __bf16 bf16x8 __attribute__((ext_vector_type(8)));
typedef float  f32x4  __attribute__((ext_vector_type(4)));

typedef unsigned int __attribute__((address_space(1))) as1_uint;
typedef unsigned int __attribute__((address_space(3))) as3_uint;

__device__ __forceinline__ void gload_lds16(const void* g, void* l) {
    __builtin_amdgcn_global_load_lds((const as1_uint*)g, (as3_uint*)l, 16, 0, 0);
}

__device__ __forceinline__ unsigned short f2bf(float f) {
    unsigned int u = __float_as_uint(f);
    return (unsigned short)((u + 0x7fffu + ((u >> 16) & 1u)) >> 16);  // RNE
}

// ---------------------------------------------------------------------------
// 64x64 transpose-convert: src (e,Ks,Ns) f32 tile (kt,nt) -> dst (e,dR,Ks) bf16.
// VEC: float4 phase-1 loads (needs Ns%4==0). sh: 64*66 ushorts. 256 threads.
template <bool VEC>
__device__ __forceinline__ void trans64(const float* __restrict__ src,
                                        unsigned short* __restrict__ dst,
                                        int Ks, int Ns, int dR, int e, int kt,
                                        int nt, unsigned short* sh, int tid) {
    int k0 = kt * 64, n0 = nt * 64;
    const float* s = src + (size_t)e * Ks * Ns + (size_t)k0 * Ns + n0;
    unsigned short* d = dst + ((size_t)e * dR + n0) * Ks + k0;
    if (VEC) {
        int c4 = tid & 15;
#pragma unroll
        for (int p = 0; p < 4; p++) {
            int r = (tid >> 4) + p * 16;
            float4 v = *(const float4*)&s[(size_t)r * Ns + c4 * 4];
            ushort4 o;
            o.x = f2bf(v.x); o.y = f2bf(v.y); o.z = f2bf(v.z); o.w = f2bf(v.w);
            *(ushort4*)&sh[r * 66 + c4 * 4] = o;
        }
    } else {
        int tx = tid & 63;
#pragma unroll
        for (int p = 0; p < 16; p++) {
            int r = (tid >> 6) + p * 4;
            sh[r * 66 + tx] = f2bf(s[(size_t)r * Ns + tx]);
        }
    }
    __syncthreads();
    int kq = tid & 15;
#pragma unroll
    for (int p = 0; p < 4; p++) {
        int n = (tid >> 4) + p * 16;
        ushort4 o;
        o.x = sh[(kq * 4 + 0) * 66 + n];
        o.y = sh[(kq * 4 + 1) * 66 + n];
        o.z = sh[(kq * 4 + 2) * 66 + n];
        o.w = sh[(kq * 4 + 3) * 66 + n];
        *(ushort4*)&d[(size_t)n * Ks + kq * 4] = o;
    }
}

// ---------------------------------------------------------------------------
// Uber prep. XCD-pinned segments: every weight-transpose block has e = bid%8,
// so expert e's transposed weights are produced (and stay dirty) in XCD e's L2.
// Segments: [0,2048) W2T | [2048,2688) W1T | [2688,3200) W3T | [3200,3520) x
//           [3520,3528) rcol | 3528 bucket
__global__ __launch_bounds__(256)
void k_prep(const float* __restrict__ state, const float* __restrict__ action,
            const int* __restrict__ idx,
            const float* __restrict__ W1, const float* __restrict__ W2,
            const float* __restrict__ W3,
            unsigned short* __restrict__ xb, unsigned short* __restrict__ w1t,
            unsigned short* __restrict__ w2t, unsigned short* __restrict__ w3t,
            int* __restrict__ order, int* __restrict__ ebase,
            int* __restrict__ etot) {
    __shared__ unsigned short sh[64 * 66];
    __shared__ int scnt[16][E_NUM];
    int bid = blockIdx.x, tid = threadIdx.x;

    if (bid < 2048) {            // W2: (8,1024,1024) -> (8,1024,1024)
        int e = bid & 7, t = bid >> 3;               // t: 0..255
        trans64<true>(W2, w2t, H_DIM, H_DIM, H_DIM, e, t >> 4, t & 15, sh, tid);
        return;
    }
    if (bid < 2688) {            // W1: (8,320,1024) -> (8,1024,320)
        int a = bid - 2048, e = a & 7, t = a >> 3;   // t: 0..79
        trans64<true>(W1, w1t, IN_DIM, H_DIM, H_DIM, e, t / 16, t % 16, sh, tid);
        return;
    }
    if (bid < 3200) {            // W3 cols 0..255: (8,1024,257) -> (8,384,1024)
        int a = bid - 2688, e = a & 7, t = a >> 3;   // t: 0..63
        trans64<false>(W3, w3t, H_DIM, OUT_DIM, W3ROWS, e, t >> 2, t & 3, sh, tid);
        return;
    }
    if (bid < 3520) {            // x = concat(state, action) -> bf16
        int a = bid - 3200;
        const float4* sf = (const float4*)state;
        const float4* af = (const float4*)action;
#pragma unroll
        for (int p = 0; p < 8; p++) {
            int q = a * 2048 + p * 256 + tid;        // quad id: b*80 + j
            int b = q / 80, j = q % 80;
            float4 v = (j < 64) ? sf[b * 64 + j] : af[b * 16 + (j - 64)];
            ushort4 o;
            o.x = f2bf(v.x); o.y = f2bf(v.y); o.z = f2bf(v.z); o.w = f2bf(v.w);
            ((ushort4*)xb)[q] = o;
        }
        return;
    }
    if (bid < 3528) {            // W3 reward column -> w3t row 256
        int e = bid - 3520;
#pragma unroll
        for (int p = 0; p < 4; p++) {
            int k = p * 256 + tid;
            w3t[((size_t)e * W3ROWS + 256) * H_DIM + k] =
                f2bf(W3[((size_t)e * H_DIM + k) * OUT_DIM + 256]);
        }
        return;
    }

    // ---- bucket (1 block): order[], ebase[8], etot[8] ----
    int shard = tid & 15;
    if (tid < 128) ((int*)scnt)[tid] = 0;
    __syncthreads();
    for (int b = tid; b < B_SZ; b += 256) atomicAdd(&scnt[shard][idx[b]], 1);
    __syncthreads();
    if (tid == 0) {
        int pos = 0;
        for (int e = 0; e < E_NUM; e++) {
            int start = pos;
            for (int s = 0; s < 16; s++) { int c = scnt[s][e]; scnt[s][e] = pos; pos += c; }
            ebase[e] = start; etot[e] = pos - start;
        }
    }
    __syncthreads();
    for (int b = tid; b < B_SZ; b += 256) {
        int e = idx[b];
        int p = atomicAdd(&scnt[shard][e], 1);
        order[p] = b;
    }
}

// ---------------------------------------------------------------------------
// Grouped GEMM, XCD-pinned: e = bid%8 -> all blocks of expert e on XCD e;
// its weights + A rows (~4 MB) stay L2-resident, so tile re-reads hit L2.
// 128x128 tile, 4 waves 2x2 (64x64 each, 4x4 frags of 16x16x32 bf16 MFMA),
// BK=32, 2-stage LDS dbuf, XOR-swizzled staging (slot (row,c) holds global
// chunk c^((row>>1)&3)) -> fragment ds_read_b128 is 2-way (free).
// Wt: (E, wtRows, K) bf16 N-major.
// MODE 0: Hout[(p0+m)*1024 + n] = bf16(relu(acc + bias))
// MODE 1: n<256 -> Out[row*256+n] = state+acc+b; n==256 -> reward; else drop.
template <int K, bool GATHER, int MODE>
__global__ __launch_bounds__(256, 2)
void k_gemm(const unsigned short* __restrict__ Abase,
            const unsigned short* __restrict__ Wt, int wtRows,
            const float* __restrict__ bias, int bstride,
            unsigned short* __restrict__ Hout,
            float* __restrict__ Out, const float* __restrict__ state,
            const int* __restrict__ order,
            const int* __restrict__ ebase, const int* __restrict__ etot) {
    constexpr int NI  = K / 32;
    constexpr int ABY = 128 * 64;         // A stage bytes (128 rows x 64B)
    constexpr int STG = 2 * ABY;          // A + B per stage = 16 KB
    __shared__ __align__(16) char lds[2 * STG];

    int bid = blockIdx.x;
    int e = bid & 7, rr_ = bid >> 3;
    int mt = rr_ & (MT_MAX - 1), nt = rr_ >> 6;
    int p0 = ebase[e] + mt * TM;
    int cnt = etot[e] - mt * TM;
    if (cnt <= 0) return;
    cnt = cnt < TM ? cnt : TM;
    int n0 = nt * 128;
    int tid = threadIdx.x;
    int w = tid >> 6, lane = tid & 63;

    // staging: thread fills LDS slot (row=tid>>2, chunk=tid&3) in each 4 KB
    // half; fetches global chunk (tid&3) ^ swizzle(row). Rows r and r+64.
    int r  = tid >> 2;
    int cg = (tid & 3) ^ ((r >> 1) & 3);
    int rc0 = r < cnt ? r : cnt - 1;
    int rc1 = (r + 64) < cnt ? (r + 64) : cnt - 1;
    long ar0 = GATHER ? order[p0 + rc0] : (p0 + rc0);
    long ar1 = GATHER ? order[p0 + rc1] : (p0 + rc1);
    const unsigned short* aP0 = Abase + (size_t)ar0 * K + cg * 8;
    const unsigned short* aP1 = Abase + (size_t)ar1 * K + cg * 8;
    const unsigned short* bP0 = Wt + ((size_t)e * wtRows + n0 + r) * K + cg * 8;
    const unsigned short* bP1 = bP0 + (size_t)64 * K;

    auto stage = [&](int k0, int sb) {
        gload_lds16(aP0 + k0, lds + sb + tid * 16);
        gload_lds16(aP1 + k0, lds + sb + 4096 + tid * 16);
        gload_lds16(bP0 + k0, lds + sb + ABY + tid * 16);
        gload_lds16(bP1 + k0, lds + sb + ABY + 4096 + tid * 16);
    };

    f32x4 acc[4][4];
#pragma unroll
    for (int i = 0; i < 4; i++)
#pragma unroll
        for (int j = 0; j < 4; j++) acc[i][j] = (f32x4)0.f;

    const int m_off = (w >> 1) * 64, n_off = (w & 1) * 64;
    const int fm   = lane & 15;
    const int koff = ((lane >> 4) ^ ((fm >> 1) & 3)) * 8;  // swizzled k-chunk

    stage(0, 0);
    for (int it = 0; it < NI; ++it) {
        __syncthreads();             // drains stage(it); stage(it+1) overlaps compute(it)
        if (it + 1 < NI) stage((it + 1) * 32, ((it + 1) & 1) * STG);
        const unsigned short* As = (const unsigned short*)(lds + (it & 1) * STG);
        const unsigned short* Bs = As + ABY / 2;   // shorts

        bf16x8 af[4], bf[4];
#pragma unroll
        for (int i = 0; i < 4; i++)
            af[i] = *(const bf16x8*)&As[(m_off + i * 16 + fm) * 32 + koff];
#pragma unroll
        for (int j = 0; j < 4; j++)
            bf[j] = *(const bf16x8*)&Bs[(n_off + j * 16 + fm) * 32 + koff];
#pragma unroll
        for (int i = 0; i < 4; i++)
#pragma unroll
            for (int j = 0; j < 4; j++)
                acc[i][j] = __builtin_amdgcn_mfma_f32_16x16x32_bf16(
                    af[i], bf[j], acc[i][j], 0, 0, 0);
    }

    // epilogue: C/D mapping col = lane&15, row = (lane>>4)*4 + reg
    int col = lane & 15, rq = lane >> 4;
#pragma unroll
    for (int j = 0; j < 4; j++) {
        int n = n0 + n_off + j * 16 + col;
        float bv = (MODE == 0) ? bias[e * bstride + n]
                               : ((n <= 256) ? bias[e * bstride + n] : 0.f);
#pragma unroll
        for (int i = 0; i < 4; i++) {
#pragma unroll
            for (int rr = 0; rr < 4; rr++) {
                int m = m_off + i * 16 + rq * 4 + rr;
                if (m < cnt) {
                    float v = acc[i][j][rr] + bv;
                    if (MODE == 0) {
                        Hout[(size_t)(p0 + m) * H_DIM + n] = f2bf(fmaxf(v, 0.f));
                    } else {
                        int row = order[p0 + m];
                        if (n < 256) {
                            size_t o = (size_t)row * 256 + n;
                            Out[o] = state[o] + v;
                        } else if (n == 256) {
                            Out[(size_t)B_SZ * 256 + row] = v;   // reward
                        }
                    }
                }
            }
        }
    }
}

// ---------------------------------------------------------------------------
extern "C" void kernel_launch(void* const* d_in, const int* in_sizes, int n_in,
                              void* d_out, int out_size, void* d_ws, size_t ws_size,
                              hipStream_t stream) {
    const float* state  = (const float*)d_in[0];
    const float* action = (const float*)d_in[1];
    const int*   idx    = (const int*)d_in[2];
    const float* W1     = (const float*)d_in[3];
    const float* b1     = (const float*)d_in[4];
    const float* W2     = (const float*)d_in[5];
    const float* b2     = (const float*)d_in[6];
    const float* W3     = (const float*)d_in[7];
    const float* b3     = (const float*)d_in[8];
    float* out = (float*)d_out;

    char* ws = (char*)d_ws;
    size_t off = 0;
    auto alloc = [&](size_t bytes) -> void* {
        void* p = ws + off;
        off = (off + bytes + 255) & ~(size_t)255;
        return p;
    };
    unsigned short* xb  = (unsigned short*)alloc((size_t)B_SZ * IN_DIM * 2);
    unsigned short* w1t = (unsigned short*)alloc((size_t)E_NUM * H_DIM * IN_DIM * 2);
    unsigned short* w2t = (unsigned short*)alloc((size_t)E_NUM * H_DIM * H_DIM * 2);
    unsigned short* w3t = (unsigned short*)alloc((size_t)E_NUM * W3ROWS * H_DIM * 2);
    unsigned short* h1  = (unsigned short*)alloc((size_t)B_SZ * H_DIM * 2);
    unsigned short* h2  = (unsigned short*)alloc((size_t)B_SZ * H_DIM * 2);
    int* order = (int*)alloc(B_SZ * 4);
    int* ebase = (int*)alloc(E_NUM * 4);
    int* etot  = (int*)alloc(E_NUM * 4);

    // prep: XCD-pinned weight transposes + x-convert + reward col + bucket
    k_prep<<<3529, 256, 0, stream>>>(state, action, idx, W1, W2, W3,
                                     xb, w1t, w2t, w3t, order, ebase, etot);

    // grouped GEMMs, XCD-pinned (e = bid%8); fixed worst-case grids,
    // empty tiles early-exit. grid = 8 e * 64 mt * NT nt.
    k_gemm<IN_DIM, true, 0><<<8 * MT_MAX * 8, 256, 0, stream>>>(
        xb, w1t, H_DIM, b1, H_DIM, h1, nullptr, nullptr, order, ebase, etot);
    k_gemm<H_DIM, false, 0><<<8 * MT_MAX * 8, 256, 0, stream>>>(
        h1, w2t, H_DIM, b2, H_DIM, h2, nullptr, nullptr, order, ebase, etot);
    k_gemm<H_DIM, false, 1><<<8 * MT_MAX * 3, 256, 0, stream>>>(
        h2, w3t, W3ROWS, b3, OUT_DIM, nullptr, out, state, order, ebase, etot);
}